// Round 1
// baseline (87.662 us; speedup 1.0000x reference)
//
#include <hip/hip_runtime.h>
#include <hip/hip_bf16.h>
#include <stdint.h>

#define B_ROWS 2048
#define FEAT   2048
#define NK     128
#define ND     16
#define NCOL   2048   // NK*ND

#define BM 128
#define BN 128
#define BK 64

typedef __attribute__((ext_vector_type(4))) float f32x4;
typedef __attribute__((ext_vector_type(8))) short bf16x8;

__device__ __forceinline__ unsigned short f32_to_bf16(float f) {
    uint32_t x = __float_as_uint(f);
    uint32_t r = (x + 0x7fffu + ((x >> 16) & 1u)) >> 16;  // RNE
    return (unsigned short)r;
}

// ---------------- Kernel 1: x f32 -> bf16 (4 elems/thread) ----------------
__global__ void k_convert(const float* __restrict__ in, unsigned short* __restrict__ out, int n4) {
    int i = blockIdx.x * blockDim.x + threadIdx.x;
    if (i >= n4) return;
    float4 v = ((const float4*)in)[i];
    ushort4 o;
    o.x = f32_to_bf16(v.x); o.y = f32_to_bf16(v.y);
    o.z = f32_to_bf16(v.z); o.w = f32_to_bf16(v.w);
    ((ushort4*)out)[i] = o;
}

// ------------- Kernel 2: W [k][n] f32 -> Wt [n][k] bf16 (transpose) -------
__global__ void k_transpose(const float* __restrict__ W, unsigned short* __restrict__ Wt) {
    __shared__ float tile[32][33];
    int tx = threadIdx.x, ty = threadIdx.y;
    int n0 = blockIdx.x * 32, k0 = blockIdx.y * 32;
    #pragma unroll
    for (int i = 0; i < 4; ++i)
        tile[ty + i * 8][tx] = W[(size_t)(k0 + ty + i * 8) * NCOL + n0 + tx];
    __syncthreads();
    #pragma unroll
    for (int i = 0; i < 4; ++i)
        Wt[(size_t)(n0 + ty + i * 8) * FEAT + k0 + tx] = f32_to_bf16(tile[tx][ty + i * 8]);
}

// ---------------- Kernel 3: bf16 MFMA GEMM: C = A(2048x2048) * Wt^T -------
// A row-major [M][K] bf16, Bt row-major [N][K] bf16, C row-major [M][N] f32.
__global__ __launch_bounds__(256) void k_gemm(const unsigned short* __restrict__ A,
                                              const unsigned short* __restrict__ Bt,
                                              float* __restrict__ C) {
    __shared__ __align__(16) unsigned short As[BM * BK];  // [m][k] 16KB
    __shared__ __align__(16) unsigned short Bs[BN * BK];  // [n][k] 16KB
    const int tid  = threadIdx.x;
    const int wave = tid >> 6;
    const int lane = tid & 63;
    const int bm = blockIdx.y, bn = blockIdx.x;
    const int wm = (wave >> 1) * 64;   // wave's 64-row sub-tile
    const int wn = (wave & 1) * 64;    // wave's 64-col sub-tile

    const int srow  = lane >> 3;        // 0..7: row within an 8-row staging chunk
    const int skcol = (lane & 7) * 8;   // k element offset (8 bf16 = 16B per lane)

    f32x4 acc[4][4];
    #pragma unroll
    for (int i = 0; i < 4; ++i)
        #pragma unroll
        for (int j = 0; j < 4; ++j)
            acc[i][j] = (f32x4){0.f, 0.f, 0.f, 0.f};

    const int fr = lane & 15;          // fragment row (A) / col (B)
    const int fk = (lane >> 4) * 8;    // fragment k offset within K=32 step

    for (int kt = 0; kt < FEAT / BK; ++kt) {
        const int k0 = kt * BK;
        __syncthreads();  // previous tile's compute done before overwrite
        #pragma unroll
        for (int r = 0; r < 4; ++r) {
            const int mrow = wave * 32 + r * 8 + srow;  // == (wave*4+r)*8 + srow
            const unsigned short* ga = A  + (size_t)(bm * BM + mrow) * FEAT + k0 + skcol;
            const unsigned short* gb = Bt + (size_t)(bn * BN + mrow) * FEAT + k0 + skcol;
            unsigned short* la = As + (wave * 4 + r) * 512;  // 1KB chunk per wave-call
            unsigned short* lb = Bs + (wave * 4 + r) * 512;
            __builtin_amdgcn_global_load_lds((const __attribute__((address_space(1))) uint32_t*)ga,
                                             (__attribute__((address_space(3))) uint32_t*)la, 16, 0, 0);
            __builtin_amdgcn_global_load_lds((const __attribute__((address_space(1))) uint32_t*)gb,
                                             (__attribute__((address_space(3))) uint32_t*)lb, 16, 0, 0);
        }
        __syncthreads();  // compiler drains vmcnt(0) before barrier -> LDS ready
        #pragma unroll
        for (int kk = 0; kk < BK; kk += 32) {
            bf16x8 av[4], bv[4];
            #pragma unroll
            for (int t = 0; t < 4; ++t)
                av[t] = *(const bf16x8*)&As[(wm + t * 16 + fr) * BK + kk + fk];
            #pragma unroll
            for (int t = 0; t < 4; ++t)
                bv[t] = *(const bf16x8*)&Bs[(wn + t * 16 + fr) * BK + kk + fk];
            #pragma unroll
            for (int i = 0; i < 4; ++i)
                #pragma unroll
                for (int j = 0; j < 4; ++j)
                    acc[i][j] = __builtin_amdgcn_mfma_f32_16x16x32_bf16(av[i], bv[j], acc[i][j], 0, 0, 0);
        }
    }

    // Epilogue: D layout col = lane&15, row = (lane>>4)*4 + r  [m89/m91-verified]
    const int crow0 = bm * BM + wm + (lane >> 4) * 4;
    const int ccol0 = bn * BN + wn + (lane & 15);
    #pragma unroll
    for (int i = 0; i < 4; ++i)
        #pragma unroll
        for (int j = 0; j < 4; ++j)
            #pragma unroll
            for (int r = 0; r < 4; ++r)
                C[(size_t)(crow0 + i * 16 + r) * NCOL + ccol0 + j * 16] = acc[i][j][r];
}

// ---------------- Kernel 4: pairwise L1 + exp reduce ----------------------
// One block per batch row; thread i owns output kernel i.
__global__ __launch_bounds__(128) void k_pairwise(const float* __restrict__ Ms, float* __restrict__ Os) {
    __shared__ float row[NK * ND];  // 8KB: this batch row's 128x16 M values
    const int b = blockIdx.x;
    const int t = threadIdx.x;
    const float4* src = (const float4*)(Ms + (size_t)b * NCOL);
    float4* dst = (float4*)row;
    for (int i = t; i < NCOL / 4; i += 128) dst[i] = src[i];
    __syncthreads();
    float mi[ND];
    #pragma unroll
    for (int d = 0; d < ND; ++d) mi[d] = row[t * ND + d];
    float acc = 0.f;
    for (int j = 0; j < NK; ++j) {
        float nrm = 0.f;
        #pragma unroll
        for (int d = 0; d < ND; ++d) nrm += fabsf(mi[d] - row[j * ND + d]);
        acc += __expf(-nrm);  // j==i gives exp(0)=1 exactly
    }
    Os[(size_t)b * NK + t] = acc;
}

extern "C" void kernel_launch(void* const* d_in, const int* in_sizes, int n_in,
                              void* d_out, int out_size, void* d_ws, size_t ws_size,
                              hipStream_t stream) {
    const float* x = (const float*)d_in[0];
    const float* W = (const float*)d_in[1];
    float* Os = (float*)d_out;

    char* ws = (char*)d_ws;
    unsigned short* x_bf = (unsigned short*)ws;                          // 8MB
    unsigned short* Wt   = (unsigned short*)(ws + (size_t)8  * 1024 * 1024);  // 8MB
    float*          Ms   = (float*)        (ws + (size_t)16 * 1024 * 1024);   // 16MB

    int n4 = B_ROWS * FEAT / 4;
    k_convert<<<(n4 + 255) / 256, 256, 0, stream>>>(x, x_bf, n4);

    dim3 tb(32, 8), tg(NCOL / 32, FEAT / 32);
    k_transpose<<<tg, tb, 0, stream>>>(W, Wt);

    dim3 gg(NCOL / BN, B_ROWS / BM);  // 16 x 16 blocks
    k_gemm<<<gg, 256, 0, stream>>>(x_bf, Wt, Ms);

    k_pairwise<<<B_ROWS, 128, 0, stream>>>(Ms, Os);
}